// Round 1
// baseline (1627.960 us; speedup 1.0000x reference)
//
#include <hip/hip_runtime.h>

#define CIN  256
#define COUT 256
#define HH   96
#define WW   96
#define HW   (HH*WW)          // 9216
#define NOFF 18
#define K2C  9
#define CK   (CIN*K2C)        // 2304

// ---------------------------------------------------------------- kernel 1
// offset conv: (B,256,96,96) * (18,256,3,3) -> (B,18,96,96)
__global__ __launch_bounds__(256) void offset_conv(
        const float* __restrict__ x, const float* __restrict__ w_off,
        const float* __restrict__ b_off, float* __restrict__ offs) {
    const int tid = threadIdx.x;
    const int p   = blockIdx.x * 256 + tid;   // 0..9215
    const int co  = blockIdx.y;               // 0..17
    const int b   = blockIdx.z;
    const int ho  = p / WW, wo = p % WW;
    const float* xb = x + (size_t)b * CIN * HW;
    const float* wp = w_off + (size_t)co * CIN * 9;
    float acc = b_off[co];
    for (int ci = 0; ci < CIN; ++ci) {
        const float* xp = xb + ci * HW;
        const float* wr = wp + ci * 9;
#pragma unroll
        for (int ky = 0; ky < 3; ++ky) {
            const int y  = ho + ky - 1;
            const bool yv = (unsigned)y < (unsigned)HH;
#pragma unroll
            for (int kx = 0; kx < 3; ++kx) {
                const int xc = wo + kx - 1;
                const bool v = yv && ((unsigned)xc < (unsigned)WW);
                const float xv = v ? xp[y * WW + xc] : 0.0f;
                acc = fmaf(xv, wr[ky * 3 + kx], acc);
            }
        }
    }
    offs[((size_t)b * NOFF + co) * HW + p] = acc;
}

// ---------------------------------------------------------------- kernel 2
// w_def (256,256,3,3) -> wdT[ck][o]  (2304 x 256)
__global__ __launch_bounds__(256) void transpose_wdef(
        const float* __restrict__ w_def, float* __restrict__ wdT) {
    const int i  = blockIdx.x * 256 + threadIdx.x;   // over 2304*256
    const int o  = i & 255;
    const int ck = i >> 8;
    wdT[i] = w_def[(size_t)o * CK + ck];
}

// ---------------------------------------------------------------- kernel 3
// fused bilinear-sample + GEMM
// tile: 64 positions x 64 out-channels, K-chunk = 8 ch * 9 taps = 72
__global__ __launch_bounds__(256) void deform_main(
        const float* __restrict__ x, const float* __restrict__ offs,
        const float* __restrict__ wdT, const float* __restrict__ b_def,
        float* __restrict__ out) {
    __shared__ float A[72][68];     // [kk][pos], pitch 68 (row start 16B aligned)
    __shared__ float Bs[72][68];    // [kk][oo]
    __shared__ int   sIdx[4][576];  // [corner][k2*64+pos]
    __shared__ float sW[4][576];

    const int tid = threadIdx.x;
    const int b   = blockIdx.z;
    const int o0  = blockIdx.y * 64;
    const int p0  = blockIdx.x * 64;
    const float* xb = x + (size_t)b * CIN * HW;

    // phase 0: per-(pos,k2) corner indices & weights
    for (int e = tid; e < 576; e += 256) {
        const int pos = e & 63, k2 = e >> 6;
        const int p  = p0 + pos;
        const int ho = p / WW, wo = p % WW;
        const float offy = offs[((size_t)b * NOFF + 2 * k2    ) * HW + p];
        const float offx = offs[((size_t)b * NOFF + 2 * k2 + 1) * HW + p];
        const float py = (float)(ho - 1 + k2 / 3) + offy;
        const float px = (float)(wo - 1 + k2 % 3) + offx;
        const float y0f = floorf(py), x0f = floorf(px);
        const float wy1 = py - y0f,  wx1 = px - x0f;
        const float wy0 = 1.f - wy1, wx0 = 1.f - wx1;
        const int y0 = (int)y0f, x0 = (int)x0f;
        const int   ys[2] = {y0, y0 + 1}, xs[2] = {x0, x0 + 1};
        const float wy[2] = {wy0, wy1},  wx[2] = {wx0, wx1};
#pragma unroll
        for (int cy = 0; cy < 2; ++cy)
#pragma unroll
            for (int cx = 0; cx < 2; ++cx) {
                const int yy = ys[cy], xx = xs[cx];
                const bool v = ((unsigned)yy < (unsigned)HH) &&
                               ((unsigned)xx < (unsigned)WW);
                const int yc = min(max(yy, 0), HH - 1);
                const int xc = min(max(xx, 0), WW - 1);
                sIdx[cy * 2 + cx][e] = yc * WW + xc;
                sW  [cy * 2 + cx][e] = v ? wy[cy] * wx[cx] : 0.0f;
            }
    }

    float acc[4][4] = {};             // [pos_sub][o_sub]
    const int tx = tid & 15;          // position direction
    const int ty = tid >> 4;          // out-channel direction
    __syncthreads();

    for (int cc = 0; cc < CIN; cc += 8) {
        // stage B: wdT rows [cc*9, cc*9+72) x cols [o0, o0+64)
#pragma unroll
        for (int i = 0; i < 18; ++i) {
            const int e  = tid + i * 256;
            const int kk = e >> 6, oo = e & 63;
            Bs[kk][oo] = wdT[(size_t)(cc * 9 + kk) * COUT + o0 + oo];
        }
        // stage A: gather + bilinear
#pragma unroll
        for (int i = 0; i < 18; ++i) {
            const int e  = tid + i * 256;
            const int kk = e >> 6, pos = e & 63;
            const int c  = cc + kk / 9, k2 = kk % 9;
            const float* xp = xb + (size_t)c * HW;
            const int j = k2 * 64 + pos;
            const float v = sW[0][j] * xp[sIdx[0][j]]
                          + sW[1][j] * xp[sIdx[1][j]]
                          + sW[2][j] * xp[sIdx[2][j]]
                          + sW[3][j] * xp[sIdx[3][j]];
            A[kk][pos] = v;
        }
        __syncthreads();
#pragma unroll 8
        for (int kk = 0; kk < 72; ++kk) {
            const float4 a4 = *(const float4*)(&A [kk][tx * 4]);
            const float4 b4 = *(const float4*)(&Bs[kk][ty * 4]);
            const float av[4] = {a4.x, a4.y, a4.z, a4.w};
            const float bv[4] = {b4.x, b4.y, b4.z, b4.w};
#pragma unroll
            for (int i = 0; i < 4; ++i)
#pragma unroll
                for (int j = 0; j < 4; ++j)
                    acc[i][j] = fmaf(av[i], bv[j], acc[i][j]);
        }
        __syncthreads();
    }

    // epilogue: coalesced float4 stores along positions
#pragma unroll
    for (int j = 0; j < 4; ++j) {
        const int o = o0 + ty * 4 + j;
        const float bd = b_def[o];
        float4 v;
        v.x = acc[0][j] + bd; v.y = acc[1][j] + bd;
        v.z = acc[2][j] + bd; v.w = acc[3][j] + bd;
        *(float4*)(&out[((size_t)b * COUT + o) * HW + p0 + tx * 4]) = v;
    }
}

// ---------------------------------------------------------------- launch
extern "C" void kernel_launch(void* const* d_in, const int* in_sizes, int n_in,
                              void* d_out, int out_size, void* d_ws, size_t ws_size,
                              hipStream_t stream) {
    const float* x     = (const float*)d_in[0];
    const float* w_off = (const float*)d_in[1];
    const float* b_off = (const float*)d_in[2];
    const float* w_def = (const float*)d_in[3];
    const float* b_def = (const float*)d_in[4];
    float* out = (float*)d_out;

    float* offs = (float*)d_ws;                  // 4*18*9216 = 663552 f32
    float* wdT  = offs + (size_t)4 * NOFF * HW;  // 2304*256  f32

    dim3 g1(HW / 256, NOFF, 4);
    offset_conv<<<g1, 256, 0, stream>>>(x, w_off, b_off, offs);

    transpose_wdef<<<(CK * COUT) / 256, 256, 0, stream>>>(w_def, wdT);

    dim3 g3(HW / 64, COUT / 64, 4);
    deform_main<<<g3, 256, 0, stream>>>(x, offs, wdT, b_def, out);
}

// Round 3
// 585.125 us; speedup vs baseline: 2.7822x; 2.7822x over previous
//
#include <hip/hip_runtime.h>

typedef __attribute__((ext_vector_type(8))) _Float16 f16x8;
typedef __attribute__((ext_vector_type(4))) float f32x4;

#define HW 9216
#define CK 2304

// ---------------------------------------------------------------- pack w_def
// natural c-major k = c*9+k2. layout [kstep(72)][nfrag(16)][lane(64)][8], fp16
__global__ __launch_bounds__(256) void pack_wdef(const float* __restrict__ w_def,
                                                 _Float16* __restrict__ bp) {
    int t = blockIdx.x * 256 + threadIdx.x;     // 73728
    int lane = t & 63;
    int nfrag = (t >> 6) & 15;
    int kstep = t >> 10;
    int o = nfrag * 16 + (lane & 15);
    int kq = lane >> 4;
    f16x8 h;
#pragma unroll
    for (int j = 0; j < 8; ++j) {
        int k = kstep * 32 + kq * 8 + j;
        h[j] = (_Float16)w_def[(size_t)o * CK + k];
    }
    *(f16x8*)(bp + (size_t)(kstep * 16 + nfrag) * 512 + lane * 8) = h;
}

// ---------------------------------------------------------------- pack w_off
// layout [kstep(72)][nfrag(2)][lane(64)][8], fp16
__global__ __launch_bounds__(256) void pack_woff(const float* __restrict__ w_off,
                                                 _Float16* __restrict__ bp) {
    int t = blockIdx.x * 256 + threadIdx.x;     // 9216
    int lane = t & 63;
    int nfrag = (t >> 6) & 1;
    int kstep = t >> 7;
    int o = nfrag * 16 + (lane & 15);
    int kq = lane >> 4;
    f16x8 h;
#pragma unroll
    for (int j = 0; j < 8; ++j) {
        int k = kstep * 32 + kq * 8 + j;
        h[j] = (o < 18) ? (_Float16)w_off[(size_t)o * CK + k] : (_Float16)0.f;
    }
    *(f16x8*)(bp + (size_t)(kstep * 2 + nfrag) * 512 + lane * 8) = h;
}

// ---------------------------------------------------------------- offset conv (MFMA)
// M=64 position strip, N=32 (18 valid), K=2304. A split hi/lo fp16, B single fp16.
__global__ __launch_bounds__(256, 2) void offset_mfma(
        const float* __restrict__ x, const _Float16* __restrict__ bpo,
        const float* __restrict__ b_off, float* __restrict__ offs) {
    __shared__ _Float16 Ah[2048], Al[2048];
    const int tid = threadIdx.x;
    const int b   = blockIdx.y;
    const int p0  = blockIdx.x * 64;
    const int lane = tid & 63;
    const int wv   = __builtin_amdgcn_readfirstlane(tid >> 6);
    const int p  = p0 + lane;
    const int ho = p / 96, wo = p % 96;
    const float* xb = x + (size_t)b * 256 * HW;

    f32x4 acc[2] = {};
    for (int kstep = 0; kstep < 72; ++kstep) {
        const _Float16* bb = bpo + (size_t)kstep * 1024 + lane * 8;
        f16x8 b0 = *(const f16x8*)bb;
        f16x8 b1 = *(const f16x8*)(bb + 512);
        // stage A: im2col taps with bounds masks
        f16x8 h8, l8;
#pragma unroll
        for (int j = 0; j < 8; ++j) {
            int k  = kstep * 32 + wv * 8 + j;   // scalar per wave
            int c  = k / 9, k2 = k - 9 * c;
            int ky = k2 / 3, kx = k2 - 3 * ky;
            int y  = ho + ky - 1, xc = wo + kx - 1;
            bool vld = ((unsigned)y < 96u) && ((unsigned)xc < 96u);
            float v = vld ? xb[(size_t)c * HW + y * 96 + xc] : 0.f;
            _Float16 hh = (_Float16)v;
            h8[j] = hh;
            l8[j] = (_Float16)(v - (float)hh);
        }
        const int chs = (wv + ((lane >> 1) & 3)) & 3;
        *(f16x8*)&Ah[lane * 32 + chs * 8] = h8;
        *(f16x8*)&Al[lane * 32 + chs * 8] = l8;
        __syncthreads();
        const int r = lane & 15, kq = lane >> 4;
        const int ch = (kq + ((r >> 1) & 3)) & 3;
        const int rr = wv * 16 + r;
        f16x8 ah = *(const f16x8*)&Ah[rr * 32 + ch * 8];
        f16x8 al = *(const f16x8*)&Al[rr * 32 + ch * 8];
        acc[0] = __builtin_amdgcn_mfma_f32_16x16x32_f16(ah, b0, acc[0], 0, 0, 0);
        acc[1] = __builtin_amdgcn_mfma_f32_16x16x32_f16(ah, b1, acc[1], 0, 0, 0);
        acc[0] = __builtin_amdgcn_mfma_f32_16x16x32_f16(al, b0, acc[0], 0, 0, 0);
        acc[1] = __builtin_amdgcn_mfma_f32_16x16x32_f16(al, b1, acc[1], 0, 0, 0);
        __syncthreads();
    }
#pragma unroll
    for (int n = 0; n < 2; ++n) {
        int o = n * 16 + (lane & 15);
        if (o < 18) {
            float bo = b_off[o];
#pragma unroll
            for (int j = 0; j < 4; ++j) {
                int pl = wv * 16 + 4 * (lane >> 4) + j;
                offs[((size_t)b * 18 + o) * HW + p0 + pl] = acc[n][j] + bo;
            }
        }
    }
}

// ---------------------------------------------------------------- main fused kernel
// M=64 (8x8 tile), N=256 (4 waves x 64), K=2304 c-major. A hi/lo fp16, B single.
__global__ __launch_bounds__(256, 2) void deform_main(
        const float* __restrict__ x, const float* __restrict__ offs,
        const _Float16* __restrict__ bpm, const float* __restrict__ b_def,
        float* __restrict__ out) {
    __shared__ _Float16 Ah[2048], Al[2048];
    __shared__ union {
        struct { int4 idx[576]; float4 w[576]; } g;   // 18432 B, live in k-loop
        float T[4][1088];                             // 17408 B, epilogue only
    } u;

    const int tid = threadIdx.x;
    const int b   = blockIdx.y;
    const int th  = blockIdx.x / 12, tw = blockIdx.x % 12;
    const int h0  = th * 8, w0 = tw * 8;
    const float* xb = x + (size_t)b * 256 * HW;

    // phase 0: geometry per (k2,pos): clamped corner indices + masked weights
    for (int e = tid; e < 576; e += 256) {
        int k2 = e >> 6, i = e & 63;
        int hh = h0 + (i >> 3), ww = w0 + (i & 7);
        int p  = hh * 96 + ww;
        float offy = offs[((size_t)b * 18 + 2 * k2) * HW + p];
        float offx = offs[((size_t)b * 18 + 2 * k2 + 1) * HW + p];
        float py = (float)(hh - 1 + k2 / 3) + offy;
        float px = (float)(ww - 1 + k2 % 3) + offx;
        py = fminf(fmaxf(py, -1.0e4f), 1.0e4f);
        px = fminf(fmaxf(px, -1.0e4f), 1.0e4f);
        float y0f = floorf(py), x0f = floorf(px);
        float wy1 = py - y0f, wx1 = px - x0f;
        float wy0 = 1.f - wy1, wx0 = 1.f - wx1;
        int y0 = (int)y0f, x0 = (int)x0f;
        bool vy0 = (unsigned)y0 < 96u, vy1 = (unsigned)(y0 + 1) < 96u;
        bool vx0 = (unsigned)x0 < 96u, vx1 = (unsigned)(x0 + 1) < 96u;
        int r0 = min(max(y0, 0), 95) * 96, r1 = min(max(y0 + 1, 0), 95) * 96;
        int c0 = min(max(x0, 0), 95),      c1 = min(max(x0 + 1, 0), 95);
        u.g.idx[e] = make_int4(r0 + c0, r0 + c1, r1 + c0, r1 + c1);
        u.g.w[e]   = make_float4((vy0 && vx0) ? wy0 * wx0 : 0.f,
                                 (vy0 && vx1) ? wy0 * wx1 : 0.f,
                                 (vy1 && vx0) ? wy1 * wx0 : 0.f,
                                 (vy1 && vx1) ? wy1 * wx1 : 0.f);
    }
    __syncthreads();

    f32x4 acc[4][4] = {};
    const int lane = tid & 63;
    const int wv   = __builtin_amdgcn_readfirstlane(tid >> 6);

    for (int kstep = 0; kstep < 72; ++kstep) {
        // B fragments (L2-resident packed weights) — issue early
        const _Float16* bb = bpm + ((size_t)kstep * 16 + wv * 4) * 512 + lane * 8;
        f16x8 bf[4];
#pragma unroll
        for (int n = 0; n < 4; ++n) bf[n] = *(const f16x8*)(bb + n * 512);

        // stage A: 8 consecutive k (c-major), geometry from LDS per tap
        f16x8 h8, l8;
#pragma unroll
        for (int j = 0; j < 8; ++j) {
            int k  = kstep * 32 + wv * 8 + j;   // scalar
            int c  = k / 9, k2 = k - 9 * c;     // scalar
            const float* q = xb + (size_t)c * HW;
            int4  I = u.g.idx[k2 * 64 + lane];
            float4 W = u.g.w[k2 * 64 + lane];
            float v = W.x * q[I.x] + W.y * q[I.y] + W.z * q[I.z] + W.w * q[I.w];
            _Float16 hh = (_Float16)v;
            h8[j] = hh;
            l8[j] = (_Float16)(v - (float)hh);
        }
        const int chs = (wv + ((lane >> 1) & 3)) & 3;
        *(f16x8*)&Ah[lane * 32 + chs * 8] = h8;
        *(f16x8*)&Al[lane * 32 + chs * 8] = l8;
        __syncthreads();

        const int r = lane & 15, kq = lane >> 4;
        const int ch = (kq + ((r >> 1) & 3)) & 3;
        f16x8 ah[4], al[4];
#pragma unroll
        for (int m = 0; m < 4; ++m) {
            int rr = m * 16 + r;
            ah[m] = *(const f16x8*)&Ah[rr * 32 + ch * 8];
            al[m] = *(const f16x8*)&Al[rr * 32 + ch * 8];
        }
#pragma unroll
        for (int m = 0; m < 4; ++m)
#pragma unroll
            for (int n = 0; n < 4; ++n) {
                acc[m][n] = __builtin_amdgcn_mfma_f32_16x16x32_f16(ah[m], bf[n], acc[m][n], 0, 0, 0);
                acc[m][n] = __builtin_amdgcn_mfma_f32_16x16x32_f16(al[m], bf[n], acc[m][n], 0, 0, 0);
            }
        __syncthreads();
    }

    // epilogue: per-wave LDS transpose -> coalesced float4 stores
    {
        const int r = lane & 15, q = lane >> 4;
        float* Tw = u.T[wv];
#pragma unroll
        for (int n = 0; n < 4; ++n) {
#pragma unroll
            for (int m = 0; m < 4; ++m)
#pragma unroll
                for (int j = 0; j < 4; ++j)
                    Tw[r * 68 + m * 16 + 4 * q + j] = acc[m][n][j];
            // wave-private region; same-wave LDS ops are in-order
#pragma unroll
            for (int rep = 0; rep < 4; ++rep) {
                int ol = rep * 4 + q;
                int o  = wv * 64 + n * 16 + ol;
                const float* Tp = &Tw[ol * 68 + r * 4];
                float bd = b_def[o];
                float4 v;
                v.x = Tp[0] + bd; v.y = Tp[1] + bd; v.z = Tp[2] + bd; v.w = Tp[3] + bd;
                int i0 = r * 4;
                int prow = h0 + (i0 >> 3), pcol = w0 + (i0 & 7);
                *(float4*)&out[((size_t)b * 256 + o) * HW + prow * 96 + pcol] = v;
            }
        }
    }
}

// ---------------------------------------------------------------- launch
extern "C" void kernel_launch(void* const* d_in, const int* in_sizes, int n_in,
                              void* d_out, int out_size, void* d_ws, size_t ws_size,
                              hipStream_t stream) {
    const float* x     = (const float*)d_in[0];
    const float* w_off = (const float*)d_in[1];
    const float* b_off = (const float*)d_in[2];
    const float* w_def = (const float*)d_in[3];
    const float* b_def = (const float*)d_in[4];
    float* out = (float*)d_out;

    char* ws = (char*)d_ws;
    float*    offs = (float*)ws;                         // 2,654,208 B
    _Float16* bpm  = (_Float16*)(ws + 2654208);          // 1,179,648 B
    _Float16* bpo  = (_Float16*)(ws + 3833856);          //   147,456 B

    pack_wdef<<<288, 256, 0, stream>>>(w_def, bpm);
    pack_woff<<<36,  256, 0, stream>>>(w_off, bpo);

    dim3 g(144, 4);
    offset_mfma<<<g, 256, 0, stream>>>(x, bpo, b_off, offs);
    deform_main<<<g, 256, 0, stream>>>(x, offs, bpm, b_def, out);
}

// Round 4
// 310.358 us; speedup vs baseline: 5.2454x; 1.8853x over previous
//
#include <hip/hip_runtime.h>

typedef __attribute__((ext_vector_type(8))) _Float16 f16x8;
typedef __attribute__((ext_vector_type(4))) _Float16 f16x4;
typedef __attribute__((ext_vector_type(4))) float f32x4;

#define HW 9216
#define CK 2304

// ---------------------------------------------------------------- NHWC transpose
// x [b][256][9216] -> xT [b][9216][256]
__global__ __launch_bounds__(256) void transpose_x(const float* __restrict__ x,
                                                   float* __restrict__ xT) {
    __shared__ float tile[64][65];
    const int st = blockIdx.x, ct = blockIdx.y, b = blockIdx.z;
    const int t = threadIdx.x;
    const int lo = t & 63, hi = t >> 6;
    const float* xs = x + ((size_t)(b * 256 + ct * 64)) * HW + st * 64;
#pragma unroll
    for (int i = 0; i < 16; ++i) {
        int cl = i * 4 + hi;
        tile[cl][lo] = xs[(size_t)cl * HW + lo];
    }
    __syncthreads();
    float* xd = xT + ((size_t)(b * HW + st * 64)) * 256 + ct * 64;
#pragma unroll
    for (int i = 0; i < 16; ++i) {
        int hwl = i * 4 + hi;
        xd[(size_t)hwl * 256 + lo] = tile[lo][hwl];
    }
}

// ---------------------------------------------------------------- pack w_def
// k2-major k = k2*256 + c. layout [kstep(72)][nfrag(16)][lane(64)][8], fp16
__global__ __launch_bounds__(256) void pack_wdef(const float* __restrict__ w_def,
                                                 _Float16* __restrict__ bp) {
    int t = blockIdx.x * 256 + threadIdx.x;     // 73728
    int lane = t & 63, nfrag = (t >> 6) & 15, kstep = t >> 10;
    int o = nfrag * 16 + (lane & 15);
    int kq = lane >> 4;
    f16x8 h;
#pragma unroll
    for (int j = 0; j < 8; ++j) {
        int k = kstep * 32 + kq * 8 + j;        // k2-major index
        int k2 = k >> 8, c = k & 255;
        h[j] = (_Float16)w_def[(size_t)o * CK + c * 9 + k2];
    }
    *(f16x8*)(bp + (size_t)(kstep * 16 + nfrag) * 512 + lane * 8) = h;
}

// ---------------------------------------------------------------- pack w_off
// k2-major. layout [kstep(72)][nfrag(2)][lane(64)][8], fp16
__global__ __launch_bounds__(256) void pack_woff(const float* __restrict__ w_off,
                                                 _Float16* __restrict__ bp) {
    int t = blockIdx.x * 256 + threadIdx.x;     // 9216
    int lane = t & 63, nfrag = (t >> 6) & 1, kstep = t >> 7;
    int o = nfrag * 16 + (lane & 15);
    int kq = lane >> 4;
    f16x8 h;
#pragma unroll
    for (int j = 0; j < 8; ++j) {
        int k = kstep * 32 + kq * 8 + j;
        int k2 = k >> 8, c = k & 255;
        h[j] = (o < 18) ? (_Float16)w_off[(size_t)o * CK + c * 9 + k2] : (_Float16)0.f;
    }
    *(f16x8*)(bp + (size_t)(kstep * 2 + nfrag) * 512 + lane * 8) = h;
}

// ---------------------------------------------------------------- offset conv (MFMA)
// M=64 strip, N=32 (18 valid), K=2304 k2-major. 8 waves: wm=wv>>1 (m), wn=wv&1 (n).
__global__ __launch_bounds__(512, 4) void offset_mfma(
        const float* __restrict__ xT, const _Float16* __restrict__ bpo,
        const float* __restrict__ b_off, float* __restrict__ offs) {
    __shared__ _Float16 Ah[2][2048], Al[2][2048];
    const int tid = threadIdx.x;
    const int b   = blockIdx.y;
    const int p0  = blockIdx.x * 64;
    const int lane = tid & 63, wv = tid >> 6;
    const int wn = wv & 1, wm = wv >> 1;
    const int spos = tid >> 3, scq = tid & 7;       // staging role
    const int p  = p0 + spos;
    const int ho = p / 96, wo = p % 96;
    const float* xb = xT + (size_t)b * HW * 256;
    const int r = lane & 15, kq = lane >> 4;
    const int rr = wm * 16 + r;
    const int woff = spos * 32 + (((scq >> 1) ^ (spos & 3)) << 3) + ((scq & 1) << 2);
    const int roff = rr * 32 + ((kq ^ (rr & 3)) << 3);

    f32x4 acc = {};
    for (int kstep = 0; kstep < 72; ++kstep) {
        const int k2 = kstep >> 3, cb = (kstep & 7) * 32;
        const int ky = k2 / 3, kx = k2 - 3 * ky;
        f16x8 bfr = *(const f16x8*)(bpo + (size_t)(kstep * 2 + wn) * 512 + lane * 8);
        // stage A: masked im2col tap, 4 contiguous channels
        int y = ho + ky - 1, xx = wo + kx - 1;
        bool vld = ((unsigned)y < 96u) && ((unsigned)xx < 96u);
        float4 v = make_float4(0.f, 0.f, 0.f, 0.f);
        if (vld) v = *(const float4*)(xb + ((size_t)(y * 96 + xx)) * 256 + cb + scq * 4);
        f16x4 h4, l4;
        h4[0] = (_Float16)v.x; l4[0] = (_Float16)(v.x - (float)h4[0]);
        h4[1] = (_Float16)v.y; l4[1] = (_Float16)(v.y - (float)h4[1]);
        h4[2] = (_Float16)v.z; l4[2] = (_Float16)(v.z - (float)h4[2]);
        h4[3] = (_Float16)v.w; l4[3] = (_Float16)(v.w - (float)h4[3]);
        _Float16* AhW = Ah[kstep & 1];
        _Float16* AlW = Al[kstep & 1];
        *(f16x4*)(AhW + woff) = h4;
        *(f16x4*)(AlW + woff) = l4;
        __syncthreads();
        f16x8 ah = *(const f16x8*)(AhW + roff);
        f16x8 al = *(const f16x8*)(AlW + roff);
        acc = __builtin_amdgcn_mfma_f32_16x16x32_f16(ah, bfr, acc, 0, 0, 0);
        acc = __builtin_amdgcn_mfma_f32_16x16x32_f16(al, bfr, acc, 0, 0, 0);
    }
    const int o = wn * 16 + r;
    if (o < 18) {
        float bo = b_off[o];
#pragma unroll
        for (int j = 0; j < 4; ++j) {
            int pl = wm * 16 + 4 * kq + j;
            offs[((size_t)b * HW + p0 + pl) * 18 + o] = acc[j] + bo;
        }
    }
}

// ---------------------------------------------------------------- main fused kernel
// M=64 (8x8 tile), N=256, K=2304 k2-major. 8 waves: wm=wv>>2, wn=wv&3.
__global__ __launch_bounds__(512, 4) void deform_main(
        const float* __restrict__ xT, const float* __restrict__ offs,
        const _Float16* __restrict__ bpm, const float* __restrict__ b_def,
        float* __restrict__ out) {
    __shared__ _Float16 Ah[2][2048], Al[2][2048];
    __shared__ union {
        struct { int4 idx[576]; float4 w[576]; } g;   // 18432 B
        float T[8][16][36];                           // 18432 B (epilogue)
    } u;

    const int tid = threadIdx.x;
    const int b   = blockIdx.y;
    const int th  = blockIdx.x / 12, tw = blockIdx.x % 12;
    const int h0  = th * 8, w0 = tw * 8;
    const float* xb = xT + (size_t)b * HW * 256;

    // phase 0: geometry per (k2,pos): clamped corner offsets (x256) + masked weights
    for (int e = tid; e < 576; e += 512) {
        int k2 = e >> 6, i = e & 63;
        int hh = h0 + (i >> 3), ww = w0 + (i & 7);
        int p  = hh * 96 + ww;
        const float* op = offs + ((size_t)b * HW + p) * 18 + 2 * k2;
        float offy = op[0], offx = op[1];
        float py = (float)(hh - 1 + k2 / 3) + offy;
        float px = (float)(ww - 1 + k2 % 3) + offx;
        py = fminf(fmaxf(py, -3.0e4f), 3.0e4f);
        px = fminf(fmaxf(px, -3.0e4f), 3.0e4f);
        float y0f = floorf(py), x0f = floorf(px);
        float wy1 = py - y0f, wx1 = px - x0f;
        float wy0 = 1.f - wy1, wx0 = 1.f - wx1;
        int y0 = (int)y0f, x0 = (int)x0f;
        bool vy0 = (unsigned)y0 < 96u, vy1 = (unsigned)(y0 + 1) < 96u;
        bool vx0 = (unsigned)x0 < 96u, vx1 = (unsigned)(x0 + 1) < 96u;
        int r0 = min(max(y0, 0), 95) * 96, r1 = min(max(y0 + 1, 0), 95) * 96;
        int c0 = min(max(x0, 0), 95),      c1 = min(max(x0 + 1, 0), 95);
        u.g.idx[e] = make_int4((r0 + c0) << 8, (r0 + c1) << 8,
                               (r1 + c0) << 8, (r1 + c1) << 8);
        u.g.w[e]   = make_float4((vy0 && vx0) ? wy0 * wx0 : 0.f,
                                 (vy0 && vx1) ? wy0 * wx1 : 0.f,
                                 (vy1 && vx0) ? wy1 * wx0 : 0.f,
                                 (vy1 && vx1) ? wy1 * wx1 : 0.f);
    }
    __syncthreads();

    const int lane = tid & 63, wv = tid >> 6;
    const int wm = wv >> 2, wn = wv & 3;
    const int spos = tid >> 3, scq = tid & 7;       // staging role
    const int r = lane & 15, kq = lane >> 4;
    const int woff = spos * 32 + (((scq >> 1) ^ (spos & 3)) << 3) + ((scq & 1) << 2);

    f32x4 acc[2][4] = {};
    int4 I = make_int4(0, 0, 0, 0);
    float4 W = make_float4(0.f, 0.f, 0.f, 0.f);

    for (int kstep = 0; kstep < 72; ++kstep) {
        const int k2 = kstep >> 3, cb = (kstep & 7) * 32;
        // B fragments (L2/L1-resident packed weights)
        const _Float16* bb = bpm + ((size_t)kstep * 16 + wn * 4) * 512 + lane * 8;
        f16x8 bf[4];
#pragma unroll
        for (int n = 0; n < 4; ++n) bf[n] = *(const f16x8*)(bb + n * 512);
        // geometry registers, reloaded once per k2 phase
        if ((kstep & 7) == 0) {
            int e = k2 * 64 + spos;
            I = u.g.idx[e];
            W = u.g.w[e];
        }
        // stage A: 4 contiguous channels, 4 coalesced float4 corner loads
        const float* q = xb + cb + scq * 4;
        float4 c0 = *(const float4*)(q + I.x);
        float4 c1 = *(const float4*)(q + I.y);
        float4 c2 = *(const float4*)(q + I.z);
        float4 c3 = *(const float4*)(q + I.w);
        float4 v;
        v.x = W.x * c0.x + W.y * c1.x + W.z * c2.x + W.w * c3.x;
        v.y = W.x * c0.y + W.y * c1.y + W.z * c2.y + W.w * c3.y;
        v.z = W.x * c0.z + W.y * c1.z + W.z * c2.z + W.w * c3.z;
        v.w = W.x * c0.w + W.y * c1.w + W.z * c2.w + W.w * c3.w;
        f16x4 h4, l4;
        h4[0] = (_Float16)v.x; l4[0] = (_Float16)(v.x - (float)h4[0]);
        h4[1] = (_Float16)v.y; l4[1] = (_Float16)(v.y - (float)h4[1]);
        h4[2] = (_Float16)v.z; l4[2] = (_Float16)(v.z - (float)h4[2]);
        h4[3] = (_Float16)v.w; l4[3] = (_Float16)(v.w - (float)h4[3]);
        _Float16* AhW = Ah[kstep & 1];
        _Float16* AlW = Al[kstep & 1];
        *(f16x4*)(AhW + woff) = h4;
        *(f16x4*)(AlW + woff) = l4;
        __syncthreads();
        // A fragments + MFMA (wave owns pos wm*32..+32, channels wn*64..+64)
        f16x8 ah[2], al[2];
#pragma unroll
        for (int m = 0; m < 2; ++m) {
            int rrow = wm * 32 + m * 16 + r;
            int roff = rrow * 32 + ((kq ^ (rrow & 3)) << 3);
            ah[m] = *(const f16x8*)(AhW + roff);
            al[m] = *(const f16x8*)(AlW + roff);
        }
#pragma unroll
        for (int m = 0; m < 2; ++m)
#pragma unroll
            for (int n = 0; n < 4; ++n) {
                acc[m][n] = __builtin_amdgcn_mfma_f32_16x16x32_f16(ah[m], bf[n], acc[m][n], 0, 0, 0);
                acc[m][n] = __builtin_amdgcn_mfma_f32_16x16x32_f16(al[m], bf[n], acc[m][n], 0, 0, 0);
            }
    }

    __syncthreads();   // safe reuse of union (geometry -> T)
    // epilogue: per-wave LDS transpose -> coalesced float4 stores
    {
        float (*Tw)[36] = u.T[wv];          // [o16][pos32+pad]
        const int ol = lane >> 2;           // 0..15: o within frag
        const int pq = lane & 3;            // pos-quad
#pragma unroll
        for (int n = 0; n < 4; ++n) {
#pragma unroll
            for (int m = 0; m < 2; ++m)
#pragma unroll
                for (int j = 0; j < 4; ++j)
                    Tw[r][m * 16 + kq * 4 + j] = acc[m][n][j];
            // same-wave DS ordering guarantees write->read consistency
#pragma unroll
            for (int rep = 0; rep < 2; ++rep) {
                int posq = pq + rep * 4;    // 0..7
                int o = wn * 64 + n * 16 + ol;
                const float* Tp = &Tw[ol][posq * 4];
                float bd = b_def[o];
                float4 vv;
                vv.x = Tp[0] + bd; vv.y = Tp[1] + bd;
                vv.z = Tp[2] + bd; vv.w = Tp[3] + bd;
                int pl = wm * 32 + posq * 4;
                int py8 = pl >> 3, px8 = pl & 7;
                *(float4*)&out[((size_t)(b * 256 + o)) * HW + (h0 + py8) * 96 + w0 + px8] = vv;
            }
        }
    }
}

// ---------------------------------------------------------------- launch
extern "C" void kernel_launch(void* const* d_in, const int* in_sizes, int n_in,
                              void* d_out, int out_size, void* d_ws, size_t ws_size,
                              hipStream_t stream) {
    const float* x     = (const float*)d_in[0];
    const float* w_off = (const float*)d_in[1];
    const float* b_off = (const float*)d_in[2];
    const float* w_def = (const float*)d_in[3];
    const float* b_def = (const float*)d_in[4];
    float* out = (float*)d_out;

    char* ws = (char*)d_ws;
    float*    xT   = (float*)ws;                         // 37,748,736 B
    float*    offs = (float*)(ws + 37748736);            //  2,654,208 B
    _Float16* bpm  = (_Float16*)(ws + 40402944);         //  1,179,648 B
    _Float16* bpo  = (_Float16*)(ws + 41582592);         //    147,456 B

    dim3 gt(144, 4, 4);
    transpose_x<<<gt, 256, 0, stream>>>(x, xT);
    pack_wdef<<<288, 256, 0, stream>>>(w_def, bpm);
    pack_woff<<<36,  256, 0, stream>>>(w_off, bpo);

    dim3 g(144, 4);
    offset_mfma<<<g, 512, 0, stream>>>(xT, bpo, b_off, offs);
    deform_main<<<g, 512, 0, stream>>>(xT, offs, bpm, b_def, out);
}